// Round 4
// baseline (56.521 us; speedup 1.0000x reference)
//
#include <hip/hip_runtime.h>
#include <stdint.h>
#include <stddef.h>

typedef _Float16 f16;
typedef _Float16 f16x2 __attribute__((ext_vector_type(2)));
typedef _Float16 f16x4 __attribute__((ext_vector_type(4)));
typedef _Float16 f16x8 __attribute__((ext_vector_type(8)));
typedef float f32x4 __attribute__((ext_vector_type(4)));

#define INNER_SZ 4225
#define WK 4224          // padded K: 4096 quad + 64 linear + 64 zero
#define KQ 4096

// ---------------- prep: fold ones-column, cast W to f16 ----------------
__global__ __launch_bounds__(256) void cm_prep(const float* __restrict__ W,
                                               const float* __restrict__ bias,
                                               f16* __restrict__ Wf,
                                               float* __restrict__ cvec) {
  int idx = blockIdx.x * 256 + threadIdx.x;
  if (idx < 64 * WK) {
    int o = idx / WK;
    int k = idx - o * WK;
    float v;
    if (k < KQ) {                       // quadratic: coeff of x_i * x_j
      int i = k >> 6, j = k & 63;
      v = W[o * INNER_SZ + (i + 1) * 65 + (j + 1)];
    } else if (k < KQ + 64) {           // linear: coeff of x_j
      int j = k - KQ;
      v = W[o * INNER_SZ + (j + 1)] + W[o * INNER_SZ + (j + 1) * 65];
    } else {
      v = 0.f;                          // pad
    }
    Wf[idx] = (f16)v;
  }
  if (idx < 64) cvec[idx] = W[idx * INNER_SZ] + bias[idx];  // const + bias
}

// global -> LDS direct, 16B/lane (dest is wave-uniform base + lane*16)
__device__ inline void gload_lds16(const void* g, void* l) {
  __builtin_amdgcn_global_load_lds(
      (const __attribute__((address_space(1))) uint32_t*)(uintptr_t)g,
      (__attribute__((address_space(3))) uint32_t*)(uintptr_t)l, 16, 0, 0);
}

// ---------------- main fused kernel ----------------
// grid 512 x 256 threads (4 waves). M_TILE=128.
// Wave w owns output cols [w*16, w*16+16) for ALL 128 rows (mf=0..7).
// Each wave self-stages its own W slice -> barrier-free K-loop, counted vmcnt.
__global__ __launch_bounds__(256, 2) void cm_main(
    const float* __restrict__ x, const f16* __restrict__ Wf,
    const float* __restrict__ cvec, const float* __restrict__ gamma,
    const float* __restrict__ beta, float* __restrict__ out) {
  __shared__ __align__(16) f16 xs[128 * 72];        // x tile f16 (stride 72); reused as `part` in epilogue
  __shared__ __align__(16) f16 wbuf[4][3][2048];    // per-wave 3-deep ring: 16 cols x 128 halfK, swizzled

  const int tid = threadIdx.x;
  const int lane = tid & 63;
  const int w = tid >> 6;
  const int g = lane >> 4;
  const int c15 = lane & 15;
  const int w16 = w * 16;
  const int swz = (c15 & 7) << 4;                   // read-side XOR swizzle (bytes)
  const int mbase = blockIdx.x * 128;

// stage chunk T (global halfK [T*128, T*128+128)) of this wave's 16 cols into ring slot BI.
// LDS dest linear; source pre-swizzled with the same involution the reads use (rule #21).
// LDS layout: wbuf[w][BI][col*256B + kbyte], kbyte 16B-slot u holds W[col][u ^ (col&7)].
#define STAGE_CHUNK(T, BI)                                                 \
  _Pragma("unroll") for (int jj = 0; jj < 4; ++jj) {                       \
    int cl = 4 * jj + g;                                                   \
    int soff = (c15 * 8) ^ ((cl & 7) << 3);  /* f16 units = 16B-swizzle */ \
    gload_lds16(Wf + (size_t)(w16 + cl) * WK + (T) * 128 + soff,           \
                &wbuf[w][BI][jj * 512]);                                   \
  }

// consume quadratic chunk T from ring slot BI.
// B-frag for MFMA s: col=c15, k = s*32 + g*8 .. +7  -> byte off s*64 + g*16.
#define QUAD_CHUNK(T, BI)                                                  \
  {                                                                        \
    f16x2 xi2[8];                                                          \
    _Pragma("unroll") for (int mf = 0; mf < 8; ++mf)                       \
        xi2[mf] = *(const f16x2*)(xs + (mf * 16 + c15) * 72 + 2 * (T));    \
    const char* wb = (const char*)&wbuf[w][BI][0];                         \
    _Pragma("unroll") for (int s = 0; s < 4; ++s) {                        \
      f16x8 bf = *(const f16x8*)(wb + c15 * 256 +                          \
                                 ((s * 64 + g * 16) ^ swz));               \
      _Pragma("unroll") for (int mf = 0; mf < 8; ++mf) {                   \
        f16 xv = xi2[mf][(s >> 1)];                                        \
        f16x8 xi8 = {xv, xv, xv, xv, xv, xv, xv, xv};                      \
        f16x8 a = xi8 * xjv[mf][s & 1];                                    \
        acc[mf] = __builtin_amdgcn_mfma_f32_16x16x32_f16(a, bf, acc[mf],   \
                                                         0, 0, 0);         \
      }                                                                    \
    }                                                                      \
  }

  // ---- prologue: start W pipeline (2 chunks ahead), then x tile -> LDS ----
  STAGE_CHUNK(0, 0);
  STAGE_CHUNK(1, 1);

#pragma unroll
  for (int it = 0; it < 8; ++it) {
    int off = it * 1024 + tid * 4;
    int row = off >> 6;
    int col = off & 63;
    const float4 v = *(const float4*)(x + (size_t)(mbase + row) * 64 + col);
    f16x4 h = {(f16)v.x, (f16)v.y, (f16)v.z, (f16)v.w};
    *(f16x4*)(xs + row * 72 + col) = h;
  }
  __syncthreads();   // drains vmcnt(0): stage(0), stage(1) landed; xs visible

  // per-lane j-windows for all 8 row-fragments: x[row, p*32 + g*8 .. +7]
  f16x8 xjv[8][2];
#pragma unroll
  for (int mf = 0; mf < 8; ++mf) {
    int row = mf * 16 + c15;
#pragma unroll
    for (int p = 0; p < 2; ++p)
      xjv[mf][p] = *(const f16x8*)(xs + row * 72 + p * 32 + g * 8);
  }

  f32x4 acc[8];
#pragma unroll
  for (int mf = 0; mf < 8; ++mf) acc[mf] = (f32x4){0.f, 0.f, 0.f, 0.f};

  // ---- barrier-free K loop: 31 steady-state quad chunks ----
  int bc = 0, bs = 2;
  for (int t = 0; t < 31; ++t) {
    STAGE_CHUNK(t + 2, bs);
    asm volatile("s_waitcnt vmcnt(8)" ::: "memory");  // stages t+1,t+2 in flight; t landed
    QUAD_CHUNK(t, bc);
    bc = (bc == 2) ? 0 : bc + 1;
    bs = (bs == 2) ? 0 : bs + 1;
  }
  // t = 31 (last quad chunk): only stage(32) outstanding
  asm volatile("s_waitcnt vmcnt(4)" ::: "memory");
  QUAD_CHUNK(31, bc);
  bc = (bc == 2) ? 0 : bc + 1;   // -> slot of chunk 32
  // tail chunk 32: linear part (k 4096..4159), A = x_j; k >= 4160 is zero pad (skipped)
  asm volatile("s_waitcnt vmcnt(0)" ::: "memory");
  {
    const char* wb = (const char*)&wbuf[w][bc][0];
#pragma unroll
    for (int s = 0; s < 2; ++s) {
      f16x8 bf = *(const f16x8*)(wb + c15 * 256 + ((s * 64 + g * 16) ^ swz));
#pragma unroll
      for (int mf = 0; mf < 8; ++mf) {
        f16x8 a = xjv[mf][s];
        acc[mf] = __builtin_amdgcn_mfma_f32_16x16x32_f16(a, bf, acc[mf], 0, 0, 0);
      }
    }
  }

  // ---- epilogue: +const, LayerNorm over 64 cols (4 waves x 16 cols), store ----
  const float cv = cvec[w16 + c15];
  const float gv = gamma[w16 + c15];
  const float bv = beta[w16 + c15];

  float yv[8][4];
#pragma unroll
  for (int mf = 0; mf < 8; ++mf)
#pragma unroll
    for (int r = 0; r < 4; ++r) yv[mf][r] = acc[mf][r] + cv;

  __syncthreads();                 // all waves done reading xs -> safe to alias
  float* part = (float*)xs;        // [4][128][2] (sum, sumsq) per wave per row

  // D layout: col = lane&15, row = (lane>>4)*4 + r. Reduce this wave's 16 cols.
#pragma unroll
  for (int mf = 0; mf < 8; ++mf) {
#pragma unroll
    for (int r = 0; r < 4; ++r) {
      float s = yv[mf][r];
      float q = yv[mf][r] * yv[mf][r];
#pragma unroll
      for (int m = 1; m <= 8; m <<= 1) {
        s += __shfl_xor(s, m);
        q += __shfl_xor(q, m);
      }
      if (c15 == 0) {
        int row = mf * 16 + g * 4 + r;
        part[(w * 128 + row) * 2 + 0] = s;
        part[(w * 128 + row) * 2 + 1] = q;
      }
    }
  }
  __syncthreads();
#pragma unroll
  for (int mf = 0; mf < 8; ++mf) {
#pragma unroll
    for (int r = 0; r < 4; ++r) {
      int row = mf * 16 + g * 4 + r;
      float s = part[row * 2 + 0] + part[(128 + row) * 2 + 0] +
                part[(256 + row) * 2 + 0] + part[(384 + row) * 2 + 0];
      float q = part[row * 2 + 1] + part[(128 + row) * 2 + 1] +
                part[(256 + row) * 2 + 1] + part[(384 + row) * 2 + 1];
      float mean = s * 0.015625f;
      float var = q * 0.015625f - mean * mean;
      float rstd = rsqrtf(var + 1e-6f);
      out[(size_t)(mbase + row) * 64 + w16 + c15] =
          gv * (yv[mf][r] - mean) * rstd + bv;
    }
  }
#undef STAGE_CHUNK
#undef QUAD_CHUNK
}

extern "C" void kernel_launch(void* const* d_in, const int* in_sizes, int n_in,
                              void* d_out, int out_size, void* d_ws, size_t ws_size,
                              hipStream_t stream) {
  const float* x     = (const float*)d_in[0];
  const float* W     = (const float*)d_in[1];
  const float* bias  = (const float*)d_in[2];
  const float* gamma = (const float*)d_in[3];
  const float* beta  = (const float*)d_in[4];
  float* out = (float*)d_out;

  f16* Wf = (f16*)d_ws;                                  // 64*4224*2 = 540672 B
  float* cvec = (float*)((char*)d_ws + 64 * WK * 2);     // 64 f32

  cm_prep<<<(64 * WK + 255) / 256, 256, 0, stream>>>(W, bias, Wf, cvec);
  cm_main<<<512, 256, 0, stream>>>(x, Wf, cvec, gamma, beta, out);
}

// Round 5
// 48.918 us; speedup vs baseline: 1.1554x; 1.1554x over previous
//
#include <hip/hip_runtime.h>
#include <stdint.h>
#include <stddef.h>

typedef _Float16 f16;
typedef _Float16 f16x2 __attribute__((ext_vector_type(2)));
typedef _Float16 f16x4 __attribute__((ext_vector_type(4)));
typedef _Float16 f16x8 __attribute__((ext_vector_type(8)));
typedef float f32x4 __attribute__((ext_vector_type(4)));

#define INNER_SZ 4225
#define WK 4224          // padded K: 4096 quad + 64 linear + 64 zero
#define KQ 4096
#define XSTR 72          // xs leading-dim pad (bank-friendly)

// ---------------- prep: fold ones-column, cast W to f16 ----------------
__global__ __launch_bounds__(256) void cm_prep(const float* __restrict__ W,
                                               const float* __restrict__ bias,
                                               f16* __restrict__ Wf,
                                               float* __restrict__ cvec) {
  int idx = blockIdx.x * 256 + threadIdx.x;
  if (idx < 64 * WK) {
    int o = idx / WK;
    int k = idx - o * WK;
    float v;
    if (k < KQ) {                       // quadratic: coeff of x_i * x_j
      int i = k >> 6, j = k & 63;
      v = W[o * INNER_SZ + (i + 1) * 65 + (j + 1)];
    } else if (k < KQ + 64) {           // linear: coeff of x_j
      int j = k - KQ;
      v = W[o * INNER_SZ + (j + 1)] + W[o * INNER_SZ + (j + 1) * 65];
    } else {
      v = 0.f;                          // pad
    }
    Wf[idx] = (f16)v;
  }
  if (idx < 64) cvec[idx] = W[idx * INNER_SZ] + bias[idx];  // const + bias
}

// global -> LDS direct, 16B/lane (dest is wave-uniform base + lane*16)
__device__ inline void gload_lds16(const void* g, void* l) {
  __builtin_amdgcn_global_load_lds(
      (const __attribute__((address_space(1))) uint32_t*)(uintptr_t)g,
      (__attribute__((address_space(3))) uint32_t*)(uintptr_t)l, 16, 0, 0);
}

// ---------------- main fused kernel ----------------
// grid 512 x 256 threads (4 waves). Block tile: 128 rows x 64 cols.
// Wave (mg=w&1, ng=w>>1): rows mg*64+[0,64), cols ng*32+[0,32)  -> each A-frag feeds 2 MFMAs.
// Shared W ring: 4 slots x 8KB (64 cols x 64 halfK, XOR-swizzled), one chunk = one i-index.
// Pipeline: raw s_barrier + counted vmcnt (never drain in-loop), setprio around MFMA.
__global__ __launch_bounds__(256, 3) void cm_main(
    const float* __restrict__ x, const f16* __restrict__ Wf,
    const float* __restrict__ cvec, const float* __restrict__ gamma,
    const float* __restrict__ beta, float* __restrict__ out) {
  __shared__ __align__(16) f16 xs[128 * XSTR];   // 18432 B; reused as `part` in epilogue
  __shared__ __align__(16) f16 wbuf[4][4096];    // 4 x 8192 B ring, shared by all waves

  const int tid = threadIdx.x;
  const int lane = tid & 63;
  const int w = tid >> 6;
  const int g = lane >> 4;
  const int c15 = lane & 15;
  const int mg = w & 1;
  const int ng = w >> 1;
  const int swz = (c15 & 7) << 4;                // read-side XOR swizzle (bytes)
  const int mbase = blockIdx.x * 128;

  // staging source pieces: wave w stages cols [16w,16w+16) of the chunk (2 x 1KB DMA)
  const int scol0 = 16 * w + (lane >> 3);                 // j=2w load: cols 16w..16w+7
  const int sgran = ((lane & 7) ^ (lane >> 3)) * 8;       // pre-swizzled k-granule (f16 units)

#define STAGE(T, S)                                                       \
  do {                                                                    \
    gload_lds16(Wf + (size_t)scol0 * WK + (T) * 64 + sgran,               \
                &wbuf[S][(2 * w) * 512]);                                 \
    gload_lds16(Wf + (size_t)(scol0 + 8) * WK + (T) * 64 + sgran,         \
                &wbuf[S][(2 * w + 1) * 512]);                             \
  } while (0)

  // ---- prologue: start W pipeline, stage x tile ----
  STAGE(0, 0);
  STAGE(1, 1);

#pragma unroll
  for (int it = 0; it < 8; ++it) {
    int off = it * 1024 + tid * 4;
    int row = off >> 6;
    int col = off & 63;
    const float4 v = *(const float4*)(x + (size_t)(mbase + row) * 64 + col);
    f16x4 h = {(f16)v.x, (f16)v.y, (f16)v.z, (f16)v.w};
    *(f16x4*)(xs + row * XSTR + col) = h;
  }
  __syncthreads();   // xs visible to all waves; also drains stages 0,1 (prologue only)

  // per-lane j-windows: xjv[mf][s] = x[row, s*32 + g*8 .. +7]
  f16x8 xjv[4][2];
#pragma unroll
  for (int mf = 0; mf < 4; ++mf) {
    int row = mg * 64 + mf * 16 + c15;
#pragma unroll
    for (int s = 0; s < 2; ++s)
      xjv[mf][s] = *(const f16x8*)(xs + row * XSTR + s * 32 + g * 8);
  }

  f32x4 acc[4][2];
#pragma unroll
  for (int mf = 0; mf < 4; ++mf)
#pragma unroll
    for (int nf = 0; nf < 2; ++nf)
      acc[mf][nf] = (f32x4){0.f, 0.f, 0.f, 0.f};

  // consume quadratic chunk T (i = T) from slot S
  auto quad = [&](int T, int S) {
    uint32_t sp[4];                      // per-row splat of x_i, built once per chunk
#pragma unroll
    for (int mf = 0; mf < 4; ++mf) {
      int row = mg * 64 + mf * 16 + c15;
      uint32_t u = *(const uint16_t*)(xs + row * XSTR + T);
      sp[mf] = u | (u << 16);
    }
    const char* wb = (const char*)&wbuf[S][0];
#pragma unroll
    for (int s = 0; s < 2; ++s) {
      const int ko = (s * 64 + g * 16) ^ swz;
      f16x8 bf0 = *(const f16x8*)(wb + (ng * 32 + c15) * 128 + ko);
      f16x8 bf1 = *(const f16x8*)(wb + (ng * 32 + 16 + c15) * 128 + ko);
#pragma unroll
      for (int mf = 0; mf < 4; ++mf) {
        f16x2 spv = __builtin_bit_cast(f16x2, sp[mf]);
        f16x8 xv = xjv[mf][s];
        f16x8 a;
#pragma unroll
        for (int e = 0; e < 4; ++e)
          ((f16x2*)&a)[e] = spv * ((f16x2*)&xv)[e];   // 4x v_pk_mul_f16
        acc[mf][0] = __builtin_amdgcn_mfma_f32_16x16x32_f16(a, bf0, acc[mf][0], 0, 0, 0);
        acc[mf][1] = __builtin_amdgcn_mfma_f32_16x16x32_f16(a, bf1, acc[mf][1], 0, 0, 0);
      }
    }
  };

  // ---- K loop: chunks 0..64 (64 quad + 1 linear), ring-4, 1 raw barrier/chunk ----
  for (int t = 0; t < 63; ++t) {
    STAGE(t + 2, (t + 2) & 3);
    asm volatile("s_waitcnt vmcnt(4)" ::: "memory");   // own chunk-t loads landed
    __builtin_amdgcn_s_barrier();                      // all waves' chunk-t loads landed
    __builtin_amdgcn_s_setprio(1);
    quad(t, t & 3);
    __builtin_amdgcn_s_setprio(0);
  }
  // t = 63: no more staging; chunk 64 (2 loads) still in flight
  asm volatile("s_waitcnt vmcnt(2)" ::: "memory");
  __builtin_amdgcn_s_barrier();
  __builtin_amdgcn_s_setprio(1);
  quad(63, 63 & 3);
  __builtin_amdgcn_s_setprio(0);
  // chunk 64: linear part (k 4096..4159), A = x_j directly; slot 64&3 = 0
  asm volatile("s_waitcnt vmcnt(0)" ::: "memory");
  __builtin_amdgcn_s_barrier();
  {
    const char* wb = (const char*)&wbuf[0][0];
#pragma unroll
    for (int s = 0; s < 2; ++s) {
      const int ko = (s * 64 + g * 16) ^ swz;
      f16x8 bf0 = *(const f16x8*)(wb + (ng * 32 + c15) * 128 + ko);
      f16x8 bf1 = *(const f16x8*)(wb + (ng * 32 + 16 + c15) * 128 + ko);
#pragma unroll
      for (int mf = 0; mf < 4; ++mf) {
        f16x8 a = xjv[mf][s];
        acc[mf][0] = __builtin_amdgcn_mfma_f32_16x16x32_f16(a, bf0, acc[mf][0], 0, 0, 0);
        acc[mf][1] = __builtin_amdgcn_mfma_f32_16x16x32_f16(a, bf1, acc[mf][1], 0, 0, 0);
      }
    }
  }

  // ---- epilogue: +const, LayerNorm over 64 cols (2 ng-halves combined in LDS) ----
  const float cv0 = cvec[ng * 32 + c15],      cv1 = cvec[ng * 32 + 16 + c15];
  const float gv0 = gamma[ng * 32 + c15],     gv1 = gamma[ng * 32 + 16 + c15];
  const float bv0 = beta[ng * 32 + c15],      bv1 = beta[ng * 32 + 16 + c15];

  float yv[4][2][4];
#pragma unroll
  for (int mf = 0; mf < 4; ++mf)
#pragma unroll
    for (int r = 0; r < 4; ++r) {
      yv[mf][0][r] = acc[mf][0][r] + cv0;
      yv[mf][1][r] = acc[mf][1][r] + cv1;
    }

  __syncthreads();                 // everyone done with xs/wbuf -> safe to alias
  float* part = (float*)xs;        // [2 ng][128 rows][2] (sum, sumsq)

  // D layout: col = lane&15, row = (lane>>4)*4 + r. Reduce this wave's 32 cols.
#pragma unroll
  for (int mf = 0; mf < 4; ++mf) {
#pragma unroll
    for (int r = 0; r < 4; ++r) {
      float s2 = yv[mf][0][r] + yv[mf][1][r];
      float q2 = yv[mf][0][r] * yv[mf][0][r] + yv[mf][1][r] * yv[mf][1][r];
#pragma unroll
      for (int m = 1; m <= 8; m <<= 1) {
        s2 += __shfl_xor(s2, m);
        q2 += __shfl_xor(q2, m);
      }
      if (c15 == 0) {
        int row = mg * 64 + mf * 16 + g * 4 + r;
        part[(ng * 128 + row) * 2 + 0] = s2;
        part[(ng * 128 + row) * 2 + 1] = q2;
      }
    }
  }
  __syncthreads();
#pragma unroll
  for (int mf = 0; mf < 4; ++mf) {
#pragma unroll
    for (int r = 0; r < 4; ++r) {
      int row = mg * 64 + mf * 16 + g * 4 + r;
      float s2 = part[row * 2 + 0] + part[(128 + row) * 2 + 0];
      float q2 = part[row * 2 + 1] + part[(128 + row) * 2 + 1];
      float mean = s2 * 0.015625f;
      float var = q2 * 0.015625f - mean * mean;
      float rstd = rsqrtf(var + 1e-6f);
      out[(size_t)(mbase + row) * 64 + ng * 32 + c15] =
          gv0 * (yv[mf][0][r] - mean) * rstd + bv0;
      out[(size_t)(mbase + row) * 64 + ng * 32 + 16 + c15] =
          gv1 * (yv[mf][1][r] - mean) * rstd + bv1;
    }
  }
#undef STAGE
}

extern "C" void kernel_launch(void* const* d_in, const int* in_sizes, int n_in,
                              void* d_out, int out_size, void* d_ws, size_t ws_size,
                              hipStream_t stream) {
  const float* x     = (const float*)d_in[0];
  const float* W     = (const float*)d_in[1];
  const float* bias  = (const float*)d_in[2];
  const float* gamma = (const float*)d_in[3];
  const float* beta  = (const float*)d_in[4];
  float* out = (float*)d_out;

  f16* Wf = (f16*)d_ws;                                  // 64*4224*2 = 540672 B
  float* cvec = (float*)((char*)d_ws + 64 * WK * 2);     // 64 f32

  cm_prep<<<(64 * WK + 255) / 256, 256, 0, stream>>>(W, bias, Wf, cvec);
  cm_main<<<512, 256, 0, stream>>>(x, Wf, cvec, gamma, beta, out);
}

// Round 6
// 48.688 us; speedup vs baseline: 1.1609x; 1.0047x over previous
//
#include <hip/hip_runtime.h>
#include <stdint.h>
#include <stddef.h>

typedef _Float16 f16;
typedef _Float16 f16x2 __attribute__((ext_vector_type(2)));
typedef _Float16 f16x4 __attribute__((ext_vector_type(4)));
typedef _Float16 f16x8 __attribute__((ext_vector_type(8)));
typedef float f32x4 __attribute__((ext_vector_type(4)));

#define INNER_SZ 4225
#define WK 4224          // padded K: 4096 quad + 64 linear + 64 zero
#define KQ 4096
#define XSTR 72          // xs leading-dim pad

// ---------------- prep: fold ones-column, cast W to f16 ----------------
__global__ __launch_bounds__(256) void cm_prep(const float* __restrict__ W,
                                               const float* __restrict__ bias,
                                               f16* __restrict__ Wf,
                                               float* __restrict__ cvec) {
  int idx = blockIdx.x * 256 + threadIdx.x;
  if (idx < 64 * WK) {
    int o = idx / WK;
    int k = idx - o * WK;
    float v;
    if (k < KQ) {                       // quadratic: coeff of x_i * x_j
      int i = k >> 6, j = k & 63;
      v = W[o * INNER_SZ + (i + 1) * 65 + (j + 1)];
    } else if (k < KQ + 64) {           // linear: coeff of x_j
      int j = k - KQ;
      v = W[o * INNER_SZ + (j + 1)] + W[o * INNER_SZ + (j + 1) * 65];
    } else {
      v = 0.f;                          // pad
    }
    Wf[idx] = (f16)v;
  }
  if (idx < 64) cvec[idx] = W[idx * INNER_SZ] + bias[idx];  // const + bias
}

// global -> LDS direct, 16B/lane (dest is wave-uniform base + lane*16)
__device__ inline void gload_lds16(const void* gp, void* lp) {
  __builtin_amdgcn_global_load_lds(
      (const __attribute__((address_space(1))) uint32_t*)(uintptr_t)gp,
      (__attribute__((address_space(3))) uint32_t*)(uintptr_t)lp, 16, 0, 0);
}

// ---------------- main fused kernel ----------------
// grid 512 x 512 threads (8 waves). Block tile: 128 rows x 64 cols.
// Wave (mg=w&3, ng=w>>2): rows mg*32+[0,32), cols ng*32+[0,32).
// W ring: 5 slots x 8KB (64 cols x 64 halfK, XOR-swizzled); 1 chunk = 1 i-index.
// Pipeline: stage-3-ahead DMA (vmcnt(2)), ds_read 1-chunk-ahead into regs (Pa/Pb
// rotate), 1 raw s_barrier/chunk, setprio around MFMA cluster.
__global__ __launch_bounds__(512, 4) void cm_main(
    const float* __restrict__ x, const f16* __restrict__ Wf,
    const float* __restrict__ cvec, const float* __restrict__ gamma,
    const float* __restrict__ beta, float* __restrict__ out) {
  __shared__ __align__(16) f16 xs[128 * XSTR];   // 18432 B; aliased as `part` in epilogue
  __shared__ __align__(16) f16 wbuf[5][4096];    // 5 x 8192 B ring

  const int tid = threadIdx.x;
  const int lane = tid & 63;
  const int w = tid >> 6;
  const int g = lane >> 4;
  const int c15 = lane & 15;
  const int mg = w & 3;
  const int ng = w >> 2;
  const int swz = (c15 & 7) << 4;                // read-side XOR swizzle (bytes)
  const int mbase = blockIdx.x * 128;

  // staging: wave w stages cols [8w, 8w+8) of each chunk (1 x 1KB DMA)
  const int scol = w * 8 + (lane >> 3);
  const int sgran = ((lane & 7) ^ (lane >> 3)) * 8;   // pre-swizzled k-granule (f16)

#define STAGE(T, S)                                                        \
  gload_lds16(Wf + (size_t)scol * WK + (T) * 64 + sgran,                   \
              (char*)&wbuf[(S)][0] + w * 1024)

  struct Pre { f16x8 bf[2][2]; uint32_t sp[2]; };

#define PREF(P, CC, SLOT, LOADXI)                                          \
  do {                                                                     \
    const char* wb_ = (const char*)&wbuf[(SLOT)][0];                       \
    _Pragma("unroll") for (int s_ = 0; s_ < 2; ++s_)                       \
      _Pragma("unroll") for (int nf_ = 0; nf_ < 2; ++nf_)                  \
        (P).bf[s_][nf_] = *(const f16x8*)(wb_ +                            \
            (ng * 32 + nf_ * 16 + c15) * 128 +                             \
            ((s_ * 64 + g * 16) ^ swz));                                   \
    if (LOADXI) {                                                          \
      _Pragma("unroll") for (int mf_ = 0; mf_ < 2; ++mf_) {                \
        uint32_t u_ = *(const uint16_t*)(xs +                              \
            (mg * 32 + mf_ * 16 + c15) * XSTR + (CC));                     \
        (P).sp[mf_] = u_ | (u_ << 16);                                     \
      }                                                                    \
    }                                                                      \
  } while (0)

#define QUADM(P)                                                           \
  do {                                                                     \
    _Pragma("unroll") for (int s_ = 0; s_ < 2; ++s_)                       \
      _Pragma("unroll") for (int mf_ = 0; mf_ < 2; ++mf_) {                \
        f16x2 spv_ = __builtin_bit_cast(f16x2, (P).sp[mf_]);               \
        f16x8 xv_ = xjv[mf_][s_];                                          \
        f16x8 a_;                                                          \
        _Pragma("unroll") for (int e_ = 0; e_ < 4; ++e_)                   \
          ((f16x2*)&a_)[e_] = spv_ * ((f16x2*)&xv_)[e_];                   \
        acc[mf_][0] = __builtin_amdgcn_mfma_f32_16x16x32_f16(              \
            a_, (P).bf[s_][0], acc[mf_][0], 0, 0, 0);                      \
        acc[mf_][1] = __builtin_amdgcn_mfma_f32_16x16x32_f16(              \
            a_, (P).bf[s_][1], acc[mf_][1], 0, 0, 0);                      \
      }                                                                    \
  } while (0)

#define ITER(TT, PC, PN, DOSTG, VMNSTR, LOADXI)                            \
  do {                                                                     \
    if (DOSTG) STAGE((TT) + 3, slS);                                       \
    asm volatile("s_waitcnt vmcnt(" VMNSTR ")" ::: "memory");              \
    __builtin_amdgcn_s_barrier();                                          \
    PREF(PN, (TT) + 1, slR, LOADXI);                                       \
    __builtin_amdgcn_s_setprio(1);                                         \
    QUADM(PC);                                                             \
    __builtin_amdgcn_s_setprio(0);                                         \
    slS = (slS == 4) ? 0 : slS + 1;                                        \
    slR = (slR == 4) ? 0 : slR + 1;                                        \
  } while (0)

  // ---- prologue: start W pipeline (3 ahead), stage x tile ----
  STAGE(0, 0);
  STAGE(1, 1);
  STAGE(2, 2);

#pragma unroll
  for (int it = 0; it < 4; ++it) {
    int off = it * 2048 + tid * 4;
    int row = off >> 6;
    int col = off & 63;
    const float4 v = *(const float4*)(x + (size_t)(mbase + row) * 64 + col);
    f16x4 h = {(f16)v.x, (f16)v.y, (f16)v.z, (f16)v.w};
    *(f16x4*)(xs + row * XSTR + col) = h;
  }
  __syncthreads();   // xs visible; drains DMA 0..2 (prologue only)

  // per-lane j-windows: xjv[mf][s] = x[row, s*32 + g*8 .. +7]
  f16x8 xjv[2][2];
#pragma unroll
  for (int mf = 0; mf < 2; ++mf) {
    int row = mg * 32 + mf * 16 + c15;
#pragma unroll
    for (int s = 0; s < 2; ++s)
      xjv[mf][s] = *(const f16x8*)(xs + row * XSTR + s * 32 + g * 8);
  }

  f32x4 acc[2][2];
#pragma unroll
  for (int mf = 0; mf < 2; ++mf) {
    acc[mf][0] = (f32x4){0.f, 0.f, 0.f, 0.f};
    acc[mf][1] = (f32x4){0.f, 0.f, 0.f, 0.f};
  }

  Pre Pa, Pb;
  int slS = 3, slR = 0;
  PREF(Pa, 0, 0, 1);           // chunk 0 regs (slot 0 landed via syncthreads)
  slR = 1;

  // ---- K loop: quad chunks 0..63, then linear chunk 64 ----
  for (int t = 0; t < 60; t += 2) {
    ITER(t,     Pa, Pb, 1, "2", 1);
    ITER(t + 1, Pb, Pa, 1, "2", 1);
  }
  ITER(60, Pa, Pb, 1, "2", 1);   // stages chunk 63
  ITER(61, Pb, Pa, 1, "2", 1);   // stages chunk 64
  ITER(62, Pa, Pb, 0, "1", 1);
  ITER(63, Pb, Pa, 0, "0", 0);   // prefetch chunk 64 (bf only)
  // chunk 64: linear part (k 4096..4159), A = x_j directly
  __builtin_amdgcn_s_setprio(1);
#pragma unroll
  for (int s = 0; s < 2; ++s)
#pragma unroll
    for (int mf = 0; mf < 2; ++mf) {
      f16x8 a = xjv[mf][s];
      acc[mf][0] = __builtin_amdgcn_mfma_f32_16x16x32_f16(a, Pa.bf[s][0], acc[mf][0], 0, 0, 0);
      acc[mf][1] = __builtin_amdgcn_mfma_f32_16x16x32_f16(a, Pa.bf[s][1], acc[mf][1], 0, 0, 0);
    }
  __builtin_amdgcn_s_setprio(0);

  // ---- epilogue: +const, LayerNorm over 64 cols (2 ng-halves via LDS) ----
  const float cv0 = cvec[ng * 32 + c15],  cv1 = cvec[ng * 32 + 16 + c15];
  const float gv0 = gamma[ng * 32 + c15], gv1 = gamma[ng * 32 + 16 + c15];
  const float bv0 = beta[ng * 32 + c15],  bv1 = beta[ng * 32 + 16 + c15];

  float yv[2][2][4];
#pragma unroll
  for (int mf = 0; mf < 2; ++mf)
#pragma unroll
    for (int r = 0; r < 4; ++r) {
      yv[mf][0][r] = acc[mf][0][r] + cv0;
      yv[mf][1][r] = acc[mf][1][r] + cv1;
    }

  __syncthreads();               // all waves done with xs/wbuf -> safe to alias
  float* part = (float*)xs;      // [2 ng][128 rows][2] (sum, sumsq)

  // D layout: col = lane&15, row = (lane>>4)*4 + r. Reduce this wave's 32 cols.
#pragma unroll
  for (int mf = 0; mf < 2; ++mf) {
#pragma unroll
    for (int r = 0; r < 4; ++r) {
      float s2 = yv[mf][0][r] + yv[mf][1][r];
      float q2 = yv[mf][0][r] * yv[mf][0][r] + yv[mf][1][r] * yv[mf][1][r];
#pragma unroll
      for (int m = 1; m <= 8; m <<= 1) {
        s2 += __shfl_xor(s2, m);
        q2 += __shfl_xor(q2, m);
      }
      if (c15 == 0) {
        int row = mg * 32 + mf * 16 + g * 4 + r;
        part[(ng * 128 + row) * 2 + 0] = s2;
        part[(ng * 128 + row) * 2 + 1] = q2;
      }
    }
  }
  __syncthreads();
#pragma unroll
  for (int mf = 0; mf < 2; ++mf) {
#pragma unroll
    for (int r = 0; r < 4; ++r) {
      int row = mg * 32 + mf * 16 + g * 4 + r;
      float s2 = part[row * 2 + 0] + part[(128 + row) * 2 + 0];
      float q2 = part[row * 2 + 1] + part[(128 + row) * 2 + 1];
      float mean = s2 * 0.015625f;
      float var = q2 * 0.015625f - mean * mean;
      float rstd = rsqrtf(var + 1e-6f);
      out[(size_t)(mbase + row) * 64 + ng * 32 + c15] =
          gv0 * (yv[mf][0][r] - mean) * rstd + bv0;
      out[(size_t)(mbase + row) * 64 + ng * 32 + 16 + c15] =
          gv1 * (yv[mf][1][r] - mean) * rstd + bv1;
    }
  }
#undef STAGE
#undef PREF
#undef QUADM
#undef ITER
}

extern "C" void kernel_launch(void* const* d_in, const int* in_sizes, int n_in,
                              void* d_out, int out_size, void* d_ws, size_t ws_size,
                              hipStream_t stream) {
  const float* x     = (const float*)d_in[0];
  const float* W     = (const float*)d_in[1];
  const float* bias  = (const float*)d_in[2];
  const float* gamma = (const float*)d_in[3];
  const float* beta  = (const float*)d_in[4];
  float* out = (float*)d_out;

  f16* Wf = (f16*)d_ws;                                  // 64*4224*2 = 540672 B
  float* cvec = (float*)((char*)d_ws + 64 * WK * 2);     // 64 f32

  cm_prep<<<(64 * WK + 255) / 256, 256, 0, stream>>>(W, bias, Wf, cvec);
  cm_main<<<512, 512, 0, stream>>>(x, Wf, cvec, gamma, beta, out);
}